// Round 3
// baseline (3509.591 us; speedup 1.0000x reference)
//
#include <hip/hip_runtime.h>

typedef unsigned short u16;
typedef unsigned long long u64;
typedef short bf16x8 __attribute__((ext_vector_type(8)));
typedef float f32x4 __attribute__((ext_vector_type(4)));

#define Bq 1024
#define Tq 256
#define Dq 128
#define Hq 512
#define GH 2048
#define Zq 64
#define GN 32
#define GM 8
#define MB 128
#define HTS 20   // HT row stride in u16: 40 B = 8B-aligned rows, spreads banks

// workspace layout (bytes)
#define XP_OFF   0ull                      // x packed [T][B][D] bf16  : 67108864 B
#define WP_OFF   (XP_OFF + 67108864ull)    // W/U packed frags 32*81920: 2621440 B
#define HB_OFF   (WP_OFF + 2621440ull)     // h double buffer 2*[B][H] : 2097152 B
#define CT_OFF   (HB_OFF + 2097152ull)     // row barrier counters     : 4096 B

__device__ __forceinline__ u16 f2bf(float f){
  unsigned int u = __builtin_bit_cast(unsigned int, f);
  u += 0x7fffu + ((u >> 16) & 1u);          // RNE; inputs finite
  return (u16)(u >> 16);
}
__device__ __forceinline__ float bf2f(u16 v){
  unsigned int u = ((unsigned int)v) << 16;
  return __builtin_bit_cast(float, u);
}
__device__ __forceinline__ float sigmf_(float x){
  return 1.0f / (1.0f + __expf(-x));
}
__device__ __forceinline__ float softplusf_(float x){
  float r = __logf(1.0f + __expf(x));
  return (x > 20.0f) ? x : r;               // guard overflow: softplus(x)->x
}

// coherent (cross-XCD) accesses: relaxed agent atomics -> global_* sc1,
// bypass the non-coherent per-XCD L2. 64-bit ops are NATIVE (no CAS loop);
// sub-dword atomics would expand to CAS storms -- never store u16 atomically.
__device__ __forceinline__ bf16x8 ld_h16(const u16* p){
  union { u64 q[2]; bf16x8 v; } u;
  const u64* q = (const u64*)p;
  u.q[0] = __hip_atomic_load(q,     __ATOMIC_RELAXED, __HIP_MEMORY_SCOPE_AGENT);
  u.q[1] = __hip_atomic_load(q + 1, __ATOMIC_RELAXED, __HIP_MEMORY_SCOPE_AGENT);
  return u.v;
}
__device__ __forceinline__ void st_h64(u64* p, u64 v){
  __hip_atomic_store(p, v, __ATOMIC_RELAXED, __HIP_MEMORY_SCOPE_AGENT);
}

// ---- pack x [B,T,D] fp32 -> [T,B,D] bf16 -------------------------------
__global__ __launch_bounds__(256) void pack_x_k(const float4* __restrict__ x,
                                                ushort4* __restrict__ xp){
  int idx = blockIdx.x * 256 + threadIdx.x;          // 8,388,608 float4s
  int t = idx >> 15, rem = idx & 32767, b = rem >> 5, d4 = rem & 31;
  float4 v = x[(size_t)b * 8192 + t * 32 + d4];
  ushort4 o;
  o.x = f2bf(v.x); o.y = f2bf(v.y); o.z = f2bf(v.z); o.w = f2bf(v.w);
  xp[idx] = o;
}

// ---- pack [W;U] into per-block MFMA B-fragment images ------------------
__global__ __launch_bounds__(256) void pack_w_k(const float* __restrict__ W,
                                                const float* __restrict__ U,
                                                u16* __restrict__ wp){
  int idx = blockIdx.x * 256 + threadIdx.x;          // 163840 threads
  int j = idx / 5120; int rem = idx % 5120;
  int kcg = rem >> 8; int rem2 = rem & 255;
  int n = rem2 >> 6; int lane = rem2 & 63;
  int col  = n * Hq + j * 16 + (lane & 15);
  int krow = kcg * 32 + ((lane >> 4) * 8);
  u16 vals[8];
  #pragma unroll
  for (int jj = 0; jj < 8; ++jj){
    int k = krow + jj;
    float v = (k < Dq) ? W[(size_t)k * GH + col] : U[(size_t)(k - Dq) * GH + col];
    vals[jj] = f2bf(v);
  }
  ushort4* dst = (ushort4*)(wp + (size_t)j * 40960 + ((size_t)(kcg * 4 + n) * 64 + lane) * 8);
  dst[0] = make_ushort4(vals[0], vals[1], vals[2], vals[3]);
  dst[1] = make_ushort4(vals[4], vals[5], vals[6], vals[7]);
}

// ---- persistent LSTM recurrence ---------------------------------------
// grid 8x32: block (i,j): batch rows i*128..+128, h-cols j*16..+16.
// Row i's 32 blocks sync via a row barrier; rows independent.
// h exchange through L3 via native 64-bit sc1 atomics; x/weights L2/LDS.
__global__ __launch_bounds__(256, 1) void lstm_k(
    const u16* __restrict__ xp, const u16* __restrict__ wp,
    const float* __restrict__ bias, u16* __restrict__ hb,
    unsigned int* __restrict__ ctr)
{
  __shared__ u16 WL[32768];                 // U-part B-frags, 64 KB
  __shared__ u16 HT[MB * HTS];              // h epilogue transpose, 5 KB
  const int bx = blockIdx.x;
  const int i = bx >> 5, j = bx & 31;
  const int tid = threadIdx.x;
  const int lane = tid & 63, wv = tid >> 6;
  const int l15 = lane & 15, quad = lane >> 4;
  const int koff = quad * 8;

  // x-part weights (K=0..127) -> registers: wx[kc][n]
  const u16* wj = wp + (size_t)j * 40960;
  bf16x8 wx[4][4];
  #pragma unroll
  for (int kc = 0; kc < 4; ++kc)
    #pragma unroll
    for (int n = 0; n < 4; ++n)
      wx[kc][n] = *(const bf16x8*)(wj + ((kc * 4 + n) * 64 + lane) * 8);

  // U-part weights (K=128..639) -> LDS
  {
    const uint4* src = (const uint4*)(wj + 8192);
    uint4* dst = (uint4*)WL;
    #pragma unroll
    for (int q = 0; q < 16; ++q) dst[tid + q * 256] = src[tid + q * 256];
  }
  __syncthreads();

  const int hc = j * 16 + l15;
  const float bi  = bias[hc];
  const float bf_ = bias[Hq + hc];
  const float bg  = bias[2 * Hq + hc];
  const float bo  = bias[3 * Hq + hc];
  const int row0 = i * MB + wv * 32 + l15;  // strip0 A-row; strip1 = +16
  float cst[2][4] = {{0.f,0.f,0.f,0.f},{0.f,0.f,0.f,0.f}};
  unsigned int* myctr = ctr + i * 32;

  // preload x fragments for t=0 (normal cached loads)
  bf16x8 ax[4][2];
  #pragma unroll
  for (int kc = 0; kc < 4; ++kc){
    ax[kc][0] = *(const bf16x8*)(xp + (size_t)row0 * Dq + kc * 32 + koff);
    ax[kc][1] = *(const bf16x8*)(xp + (size_t)(row0 + 16) * Dq + kc * 32 + koff);
  }

  for (int t = 0; t < Tq; ++t){
    f32x4 acc[2][4];
    #pragma unroll
    for (int s = 0; s < 2; ++s)
      #pragma unroll
      for (int n = 0; n < 4; ++n)
        acc[s][n] = (f32x4){0.f, 0.f, 0.f, 0.f};

    // ---- issue h loads FIRST so L3 latency overlaps part-1 MFMAs ----
    bf16x8 ah[16][2];
    if (t > 0){
      const u16* hcur = hb + (size_t)(t & 1) * (Bq * Hq);
      #pragma unroll
      for (int kc = 0; kc < 16; ++kc){
        ah[kc][0] = ld_h16(hcur + (size_t)row0 * Hq + kc * 32 + koff);
        ah[kc][1] = ld_h16(hcur + (size_t)(row0 + 16) * Hq + kc * 32 + koff);
      }
    }

    // ---- K part 1: x_t (kc 0..3), B from registers ----
    #pragma unroll
    for (int kc = 0; kc < 4; ++kc)
      #pragma unroll
      for (int n = 0; n < 4; ++n){
        acc[0][n] = __builtin_amdgcn_mfma_f32_16x16x32_bf16(ax[kc][0], wx[kc][n], acc[0][n], 0, 0, 0);
        acc[1][n] = __builtin_amdgcn_mfma_f32_16x16x32_bf16(ax[kc][1], wx[kc][n], acc[1][n], 0, 0, 0);
      }

    // ---- K part 2: h_t (kc 0..15), B from LDS ----
    if (t > 0){
      #pragma unroll
      for (int kc = 0; kc < 16; ++kc){
        #pragma unroll
        for (int n = 0; n < 4; ++n){
          bf16x8 bw = *(const bf16x8*)(WL + ((kc * 4 + n) * 64 + lane) * 8);
          acc[0][n] = __builtin_amdgcn_mfma_f32_16x16x32_bf16(ah[kc][0], bw, acc[0][n], 0, 0, 0);
          acc[1][n] = __builtin_amdgcn_mfma_f32_16x16x32_bf16(ah[kc][1], bw, acc[1][n], 0, 0, 0);
        }
      }
    }

    // ---- gate epilogue; c stays in registers; h -> LDS transpose ----
    // C-layout: col = lane&15 (= h-col), row = quad*4 + reg  [m89/m91]
    #pragma unroll
    for (int s = 0; s < 2; ++s){
      #pragma unroll
      for (int r = 0; r < 4; ++r){
        float gi = acc[s][0][r] + bi;
        float gf = acc[s][1][r] + bf_;
        float gg = acc[s][2][r] + bg;
        float go = acc[s][3][r] + bo;
        float iv = sigmf_(gi), fv = sigmf_(gf);
        float gv = softplusf_(gg), ov = sigmf_(go);
        float cn = fv * cst[s][r] + iv * gv;
        cst[s][r] = cn;
        float hv = ov * softplusf_(cn);
        int row_l = wv * 32 + s * 16 + quad * 4 + r;
        HT[row_l * HTS + l15] = f2bf(hv);
      }
    }
    __syncthreads();

    // ---- coalesced h store: native 64-bit sc1 stores, 2 per thread ----
    {
      u16* hn = hb + (size_t)((t + 1) & 1) * (Bq * Hq);
      #pragma unroll
      for (int q = 0; q < 2; ++q){
        int idx = tid + q * 256;            // 512 u64 segments
        int row_l = idx >> 2, part = idx & 3;
        u64 v = *(const u64*)(HT + row_l * HTS + part * 4);
        u64* dst = (u64*)(hn + (size_t)(i * MB + row_l) * Hq + j * 16 + part * 4);
        st_h64(dst, v);
      }
    }

    // ---- prefetch next x fragments; L3 latency hides under the barrier ----
    if (t + 1 < Tq){
      const u16* xt2 = xp + (size_t)(t + 1) * (Bq * Dq);
      bf16x8 axn[4][2];
      #pragma unroll
      for (int kc = 0; kc < 4; ++kc){
        axn[kc][0] = *(const bf16x8*)(xt2 + (size_t)row0 * Dq + kc * 32 + koff);
        axn[kc][1] = *(const bf16x8*)(xt2 + (size_t)(row0 + 16) * Dq + kc * 32 + koff);
      }

      // ---- row barrier (32 blocks); vmcnt(0) drains before s_barrier,
      // so sc1 h stores reached L3 before the arrive. ----
      __syncthreads();
      if (tid == 0){
        __hip_atomic_fetch_add(myctr, 1u, __ATOMIC_RELAXED, __HIP_MEMORY_SCOPE_AGENT);
        unsigned int target = (unsigned int)(GN * (t + 1));
        while (__hip_atomic_load(myctr, __ATOMIC_RELAXED, __HIP_MEMORY_SCOPE_AGENT) < target){
          __builtin_amdgcn_s_sleep(1);
        }
      }
      __syncthreads();

      #pragma unroll
      for (int kc = 0; kc < 4; ++kc){
        ax[kc][0] = axn[kc][0];
        ax[kc][1] = axn[kc][1];
      }
    }
  }
}

// ---- final projection: mu, logvar, z ----------------------------------
__global__ __launch_bounds__(64) void proj_k(const u16* __restrict__ h0,
    const float* __restrict__ Wm, const float* __restrict__ bm,
    const float* __restrict__ Wv, const float* __restrict__ bv,
    const float* __restrict__ eps, float* __restrict__ out)
{
  __shared__ float hs[Hq];
  int b = blockIdx.x, lane = threadIdx.x;
  const u16* hr = h0 + (size_t)b * Hq;
  #pragma unroll
  for (int q = 0; q < 8; ++q) hs[lane * 8 + q] = bf2f(hr[lane * 8 + q]);
  __syncthreads();
  float am = 0.f, av = 0.f;
  #pragma unroll 8
  for (int k = 0; k < Hq; ++k){
    float h = hs[k];
    am = fmaf(h, Wm[(size_t)k * Zq + lane], am);
    av = fmaf(h, Wv[(size_t)k * Zq + lane], av);
  }
  float mu = am + bm[lane];
  float lv = av + bv[lane];
  float z  = mu + eps[(size_t)b * Zq + lane] * expf(0.5f * lv);
  size_t o = (size_t)b * Zq + lane;
  out[o]           = mu;
  out[65536 + o]   = lv;
  out[131072 + o]  = z;
}

extern "C" void kernel_launch(void* const* d_in, const int* in_sizes, int n_in,
                              void* d_out, int out_size, void* d_ws, size_t ws_size,
                              hipStream_t stream)
{
  const float* x   = (const float*)d_in[0];
  const float* eps = (const float*)d_in[1];
  const float* W   = (const float*)d_in[2];
  const float* U   = (const float*)d_in[3];
  const float* bb  = (const float*)d_in[4];
  const float* Wm  = (const float*)d_in[5];
  const float* bm  = (const float*)d_in[6];
  const float* Wv  = (const float*)d_in[7];
  const float* bv  = (const float*)d_in[8];

  char* ws = (char*)d_ws;
  u16* xp = (u16*)(ws + XP_OFF);
  u16* wp = (u16*)(ws + WP_OFF);
  u16* hb = (u16*)(ws + HB_OFF);
  unsigned int* ctr = (unsigned int*)(ws + CT_OFF);

  hipMemsetAsync(ctr, 0, 4096, stream);
  pack_x_k<<<32768, 256, 0, stream>>>((const float4*)x, (ushort4*)xp);
  pack_w_k<<<640, 256, 0, stream>>>(W, U, wp);
  lstm_k<<<GM * GN, 256, 0, stream>>>(xp, wp, bb, hb, ctr);
  // after 256 steps, h_last sits in parity (256 & 1) == 0
  proj_k<<<Bq, 64, 0, stream>>>(hb, Wm, bm, Wv, bv, eps, (float*)d_out);
}

// Round 5
// 2523.084 us; speedup vs baseline: 1.3910x; 1.3910x over previous
//
#include <hip/hip_runtime.h>

typedef unsigned short u16;
typedef unsigned int u32;
typedef unsigned long long u64;
typedef short bf16x8 __attribute__((ext_vector_type(8)));
typedef float f32x4 __attribute__((ext_vector_type(4)));

#define Bq 1024
#define Tq 256
#define Dq 128
#define Hq 512
#define GH 2048
#define Zq 64
#define GN 32
#define GM 8
#define MB 128

// workspace layout (bytes)
#define XP_OFF   0ull                      // x packed [T][B][D] bf16  : 67108864 B
#define WP_OFF   (XP_OFF + 67108864ull)    // W/U packed frags 32*81920: 2621440 B
#define HB_OFF   (WP_OFF + 2621440ull)     // h double buffer 2*[B][H] : 2097152 B
#define CT_OFF   (HB_OFF + 2097152ull)     // probe tokens + barrier ctrs: 4096 B

#define POLL_CAP 65536                     // watchdog: never hang, fail loud

__device__ __forceinline__ u16 f2bf(float f){
  unsigned int u = __builtin_bit_cast(unsigned int, f);
  u += 0x7fffu + ((u >> 16) & 1u);          // RNE; inputs finite
  return (u16)(u >> 16);
}
__device__ __forceinline__ float bf2f(u16 v){
  unsigned int u = ((unsigned int)v) << 16;
  return __builtin_bit_cast(float, u);
}
__device__ __forceinline__ float sigmf_(float x){
  return 1.0f / (1.0f + __expf(-x));
}
__device__ __forceinline__ float softplusf_(float x){
  float r = __logf(1.0f + __expf(x));
  return (x > 20.0f) ? x : r;               // guard overflow: softplus(x)->x
}

// agent-coherent 16B load (sc1 path, reads coherence point) -- slow mode
__device__ __forceinline__ bf16x8 ld_h16_agent(const u16* p){
  union { u64 q[2]; bf16x8 v; } u;
  const u64* q = (const u64*)p;
  u.q[0] = __hip_atomic_load(q,     __ATOMIC_RELAXED, __HIP_MEMORY_SCOPE_AGENT);
  u.q[1] = __hip_atomic_load(q + 1, __ATOMIC_RELAXED, __HIP_MEMORY_SCOPE_AGENT);
  return u.v;
}
__device__ __forceinline__ void inv_l1(){
  asm volatile("buffer_inv sc0" ::: "memory");   // L1-only invalidate
}
// agent barrier helper: arrive + poll to target, watchdog-capped
__device__ __forceinline__ void agent_bar(u32* c, u32 target){
  __hip_atomic_fetch_add(c, 1u, __ATOMIC_RELAXED, __HIP_MEMORY_SCOPE_AGENT);
  for (int w = 0; w < POLL_CAP; ++w){
    if (__hip_atomic_load(c, __ATOMIC_RELAXED, __HIP_MEMORY_SCOPE_AGENT) >= target) break;
    __builtin_amdgcn_s_sleep(1);
  }
}

// ---- pack x [B,T,D] fp32 -> [T,B,D] bf16 -------------------------------
__global__ __launch_bounds__(256) void pack_x_k(const float4* __restrict__ x,
                                                ushort4* __restrict__ xp){
  int idx = blockIdx.x * 256 + threadIdx.x;          // 8,388,608 float4s
  int t = idx >> 15, rem = idx & 32767, b = rem >> 5, d4 = rem & 31;
  float4 v = x[(size_t)b * 8192 + t * 32 + d4];
  ushort4 o;
  o.x = f2bf(v.x); o.y = f2bf(v.y); o.z = f2bf(v.z); o.w = f2bf(v.w);
  xp[idx] = o;
}

// ---- pack [W;U] into per-block MFMA B-fragment images ------------------
__global__ __launch_bounds__(256) void pack_w_k(const float* __restrict__ W,
                                                const float* __restrict__ U,
                                                u16* __restrict__ wp){
  int idx = blockIdx.x * 256 + threadIdx.x;          // 163840 threads
  int j = idx / 5120; int rem = idx % 5120;
  int kcg = rem >> 8; int rem2 = rem & 255;
  int n = rem2 >> 6; int lane = rem2 & 63;
  int col  = n * Hq + j * 16 + (lane & 15);
  int krow = kcg * 32 + ((lane >> 4) * 8);
  u16 vals[8];
  #pragma unroll
  for (int jj = 0; jj < 8; ++jj){
    int k = krow + jj;
    float v = (k < Dq) ? W[(size_t)k * GH + col] : U[(size_t)(k - Dq) * GH + col];
    vals[jj] = f2bf(v);
  }
  ushort4* dst = (ushort4*)(wp + (size_t)j * 40960 + ((size_t)(kcg * 4 + n) * 64 + lane) * 8);
  dst[0] = make_ushort4(vals[0], vals[1], vals[2], vals[3]);
  dst[1] = make_ushort4(vals[4], vals[5], vals[6], vals[7]);
}

// ---- persistent LSTM recurrence ---------------------------------------
// grid 256: bx -> row i = bx&7, col j = bx>>3. Round-robin dispatch puts
// row i's 32 blocks on one XCD -> h exchange via that XCD's L2 (fast mode).
// A grid-global probe verdict picks fast vs agent-coherent slow mode; the
// barrier protocol is IDENTICAL in both modes (only h ld/st differ), and
// every spin is watchdog-capped: no configuration can hang.
__global__ __launch_bounds__(256, 1) void lstm_k(
    const u16* __restrict__ xp, const u16* __restrict__ wp,
    const float* __restrict__ bias, u16* __restrict__ hb,
    u32* __restrict__ ctr)
{
  __shared__ u16 WL[32768];                 // U-part B-frags, 64 KB
  __shared__ int sbad, sres;
  const int bx = blockIdx.x;
  const int i = bx & 7, j = bx >> 3;        // row -> XCD, col
  const int tid = threadIdx.x;
  const int lane = tid & 63, wv = tid >> 6;
  const int l15 = lane & 15, quad = lane >> 4;
  const int koff = quad * 8;

  u32* tok   = ctr;                         // [256] placement tokens
  u32* pc1   = ctr + 272;                   // probe barrier 1
  u32* pc2   = ctr + 288;                   // probe barrier 2
  u32* bad   = ctr + 304;                   // global verdict (0 = all ok)
  u32* stepc = ctr + 320 + i * 16;          // per-row step barrier ctr

  // ---- placement probe ----
  u32 xcc = __builtin_amdgcn_s_getreg(63508) & 0xffu; // hwreg(HW_REG_XCC_ID=20,0,32)
  if (tid == 0){
    tok[bx] = (xcc << 16) | ((u32)(bx + 1) & 0xffffu);  // plain store -> local L2
    sbad = 0;
  }
  __syncthreads();                           // drains vmcnt; compiler barrier
  if (tid == 0) agent_bar(pc1, 256);         // all token stores done
  __syncthreads();
  inv_l1();
  if (tid < 32){
    // row i, col tid was written by block bx' = tid*8 + i; plain load only
    // sees it if that block shares our L2 (or line escaped to L3: then xcc
    // tag still must match ours -> co-XCD).
    u32 v = tok[tid * 8 + i];
    u32 expect = (xcc << 16) | ((u32)(tid * 8 + i + 1) & 0xffffu);
    if (v != expect) atomicOr(&sbad, 1);
  }
  __syncthreads();
  if (tid == 0){
    if (sbad) __hip_atomic_fetch_or(bad, 1u, __ATOMIC_RELAXED, __HIP_MEMORY_SCOPE_AGENT);
    agent_bar(pc2, 256);                     // all verdicts merged
    sres = (int)__hip_atomic_load(bad, __ATOMIC_RELAXED, __HIP_MEMORY_SCOPE_AGENT);
  }
  __syncthreads();
  const bool fast = (sres == 0);             // grid-uniform decision

  // x-part weights (K=0..127) -> registers: wx[kc][n]
  const u16* wj = wp + (size_t)j * 40960;
  bf16x8 wx[4][4];
  #pragma unroll
  for (int kc = 0; kc < 4; ++kc)
    #pragma unroll
    for (int n = 0; n < 4; ++n)
      wx[kc][n] = *(const bf16x8*)(wj + ((kc * 4 + n) * 64 + lane) * 8);

  // U-part weights (K=128..639) -> LDS
  {
    const uint4* src = (const uint4*)(wj + 8192);
    uint4* dst = (uint4*)WL;
    #pragma unroll
    for (int q = 0; q < 16; ++q) dst[tid + q * 256] = src[tid + q * 256];
  }
  __syncthreads();

  const int hc = j * 16 + l15;
  const float bi  = bias[hc];
  const float bf_ = bias[Hq + hc];
  const float bg  = bias[2 * Hq + hc];
  const float bo  = bias[3 * Hq + hc];
  const int row0 = i * MB + wv * 32 + l15;  // strip0 A-row; strip1 = +16
  float cst[2][4] = {{0.f,0.f,0.f,0.f},{0.f,0.f,0.f,0.f}};

  for (int t = 0; t < Tq; ++t){
    f32x4 acc[2][4];
    #pragma unroll
    for (int s = 0; s < 2; ++s)
      #pragma unroll
      for (int n = 0; n < 4; ++n)
        acc[s][n] = (f32x4){0.f, 0.f, 0.f, 0.f};

    // ---- h loads first: long-latency, overlap with x loads + part-1 MFMAs ----
    bf16x8 ah[16][2];
    if (t > 0){
      const u16* hcur = hb + (size_t)(t & 1) * (Bq * Hq);
      if (fast){
        #pragma unroll
        for (int kc = 0; kc < 16; ++kc){     // plain dwordx4: local-L2 hits
          ah[kc][0] = *(const bf16x8*)(hcur + (size_t)row0 * Hq + kc * 32 + koff);
          ah[kc][1] = *(const bf16x8*)(hcur + (size_t)(row0 + 16) * Hq + kc * 32 + koff);
        }
      } else {
        #pragma unroll
        for (int kc = 0; kc < 16; ++kc){
          ah[kc][0] = ld_h16_agent(hcur + (size_t)row0 * Hq + kc * 32 + koff);
          ah[kc][1] = ld_h16_agent(hcur + (size_t)(row0 + 16) * Hq + kc * 32 + koff);
        }
      }
    }

    // ---- K part 1: x_t (kc 0..3), B from registers ----
    const u16* xt = xp + (size_t)t * (Bq * Dq);
    bf16x8 ax[4][2];
    #pragma unroll
    for (int kc = 0; kc < 4; ++kc){
      ax[kc][0] = *(const bf16x8*)(xt + (size_t)row0 * Dq + kc * 32 + koff);
      ax[kc][1] = *(const bf16x8*)(xt + (size_t)(row0 + 16) * Dq + kc * 32 + koff);
    }
    #pragma unroll
    for (int kc = 0; kc < 4; ++kc)
      #pragma unroll
      for (int n = 0; n < 4; ++n){
        acc[0][n] = __builtin_amdgcn_mfma_f32_16x16x32_bf16(ax[kc][0], wx[kc][n], acc[0][n], 0, 0, 0);
        acc[1][n] = __builtin_amdgcn_mfma_f32_16x16x32_bf16(ax[kc][1], wx[kc][n], acc[1][n], 0, 0, 0);
      }

    // ---- K part 2: h_t (kc 0..15), B from LDS ----
    if (t > 0){
      #pragma unroll
      for (int kc = 0; kc < 16; ++kc){
        #pragma unroll
        for (int n = 0; n < 4; ++n){
          bf16x8 bw = *(const bf16x8*)(WL + ((kc * 4 + n) * 64 + lane) * 8);
          acc[0][n] = __builtin_amdgcn_mfma_f32_16x16x32_bf16(ah[kc][0], bw, acc[0][n], 0, 0, 0);
          acc[1][n] = __builtin_amdgcn_mfma_f32_16x16x32_bf16(ah[kc][1], bw, acc[1][n], 0, 0, 0);
        }
      }
    }

    // ---- gate epilogue; c in registers; h stores (mode-dependent) ----
    // C-layout: col = lane&15 (= h-col), row = quad*4 + reg  [m89/m91]
    u16* hn = hb + (size_t)((t + 1) & 1) * (Bq * Hq);
    #pragma unroll
    for (int s = 0; s < 2; ++s){
      #pragma unroll
      for (int r = 0; r < 4; ++r){
        float gi = acc[s][0][r] + bi;
        float gf = acc[s][1][r] + bf_;
        float gg = acc[s][2][r] + bg;
        float go = acc[s][3][r] + bo;
        float iv = sigmf_(gi), fv = sigmf_(gf);
        float gv = softplusf_(gg), ov = sigmf_(go);
        float cn = fv * cst[s][r] + iv * gv;
        cst[s][r] = cn;
        float hv = ov * softplusf_(cn);
        int row = (row0 - l15) + s * 16 + quad * 4 + r;
        u16* dst = hn + (size_t)row * Hq + hc;
        if (fast) *dst = f2bf(hv);            // plain store -> local L2
        else __hip_atomic_store(dst, f2bf(hv), __ATOMIC_RELAXED, __HIP_MEMORY_SCOPE_AGENT);
      }
    }

    // ---- row barrier: identical protocol in both modes ----
    if (t + 1 < Tq){
      __syncthreads();                       // vmcnt(0): h stores left the CU
      if (tid == 0) agent_bar(stepc, (u32)(GN * (t + 1)));
      __syncthreads();
      if (fast) inv_l1();                    // drop stale h lines from L1
    }
  }
}

// ---- final projection: mu, logvar, z ----------------------------------
__global__ __launch_bounds__(64) void proj_k(const u16* __restrict__ h0,
    const float* __restrict__ Wm, const float* __restrict__ bm,
    const float* __restrict__ Wv, const float* __restrict__ bv,
    const float* __restrict__ eps, float* __restrict__ out)
{
  __shared__ float hs[Hq];
  int b = blockIdx.x, lane = threadIdx.x;
  const u16* hr = h0 + (size_t)b * Hq;
  #pragma unroll
  for (int q = 0; q < 8; ++q) hs[lane * 8 + q] = bf2f(hr[lane * 8 + q]);
  __syncthreads();
  float am = 0.f, av = 0.f;
  #pragma unroll 8
  for (int k = 0; k < Hq; ++k){
    float h = hs[k];
    am = fmaf(h, Wm[(size_t)k * Zq + lane], am);
    av = fmaf(h, Wv[(size_t)k * Zq + lane], av);
  }
  float mu = am + bm[lane];
  float lv = av + bv[lane];
  float z  = mu + eps[(size_t)b * Zq + lane] * expf(0.5f * lv);
  size_t o = (size_t)b * Zq + lane;
  out[o]           = mu;
  out[65536 + o]   = lv;
  out[131072 + o]  = z;
}

extern "C" void kernel_launch(void* const* d_in, const int* in_sizes, int n_in,
                              void* d_out, int out_size, void* d_ws, size_t ws_size,
                              hipStream_t stream)
{
  const float* x   = (const float*)d_in[0];
  const float* eps = (const float*)d_in[1];
  const float* W   = (const float*)d_in[2];
  const float* U   = (const float*)d_in[3];
  const float* bb  = (const float*)d_in[4];
  const float* Wm  = (const float*)d_in[5];
  const float* bm  = (const float*)d_in[6];
  const float* Wv  = (const float*)d_in[7];
  const float* bv  = (const float*)d_in[8];

  char* ws = (char*)d_ws;
  u16* xp = (u16*)(ws + XP_OFF);
  u16* wp = (u16*)(ws + WP_OFF);
  u16* hb = (u16*)(ws + HB_OFF);
  u32* ctr = (u32*)(ws + CT_OFF);

  hipMemsetAsync(ctr, 0, 4096, stream);
  pack_x_k<<<32768, 256, 0, stream>>>((const float4*)x, (ushort4*)xp);
  pack_w_k<<<640, 256, 0, stream>>>(W, U, wp);
  lstm_k<<<GM * GN, 256, 0, stream>>>(xp, wp, bb, hb, ctr);
  // after 256 steps, h_last sits in parity (256 & 1) == 0
  proj_k<<<Bq, 64, 0, stream>>>(hb, Wm, bm, Wv, bv, eps, (float*)d_out);
}